// Round 3
// baseline (137.521 us; speedup 1.0000x reference)
//
#include <hip/hip_runtime.h>

// out[i, j] = x[i, j] * a[j];  x: [65536, 1024] f32, a: [1024] f32.
// Memory-bound streaming multiply:
//  - 16B/lane fully-coalesced loads/stores (native ext_vector float4 so the
//    nontemporal builtins accept the pointer type)
//  - grid stride is a multiple of 256 column-quads -> per-thread scale is
//    loop-invariant, hoisted to registers (no LDS in hot loop)
//  - 8x unroll over stride-separated indices -> 8 independent loads in flight
//  - nontemporal load/store: pure streaming, skip cache retention

#define XSIZE 1024
#define XSIZE4 (XSIZE / 4)   // 256 float4 column-quads

typedef float f4 __attribute__((ext_vector_type(4)));

__global__ __launch_bounds__(256) void ic_adjust_kernel(
    const float* __restrict__ x,
    const float* __restrict__ a,
    float* __restrict__ out,
    long long n4) {
    const f4* __restrict__ x4 = reinterpret_cast<const f4*>(x);
    const f4* __restrict__ a4 = reinterpret_cast<const f4*>(a);
    f4* __restrict__ o4 = reinterpret_cast<f4*>(out);

    const long long tid = (long long)blockIdx.x * blockDim.x + threadIdx.x;
    const long long stride = (long long)gridDim.x * blockDim.x;

    // stride % XSIZE4 == 0 (2048*256), so (i & 255) is invariant across the
    // grid-stride loop: load this thread's column-quad scale once.
    const f4 s = a4[tid & (XSIZE4 - 1)];

    constexpr int U = 8;
    long long i = tid;
    for (; i + (U - 1) * stride < n4; i += U * stride) {
        f4 v[U];
#pragma unroll
        for (int u = 0; u < U; ++u)
            v[u] = __builtin_nontemporal_load(&x4[i + u * stride]);
#pragma unroll
        for (int u = 0; u < U; ++u) {
            v[u] *= s;
            __builtin_nontemporal_store(v[u], &o4[i + u * stride]);
        }
    }
    // tail (not taken for the benchmark shape: 32 iters % 8 == 0)
    for (; i < n4; i += stride) {
        f4 v = __builtin_nontemporal_load(&x4[i]);
        v *= s;
        __builtin_nontemporal_store(v, &o4[i]);
    }
}

extern "C" void kernel_launch(void* const* d_in, const int* in_sizes, int n_in,
                              void* d_out, int out_size, void* d_ws, size_t ws_size,
                              hipStream_t stream) {
    const float* x = (const float*)d_in[0];
    const float* a = (const float*)d_in[1];
    float* out = (float*)d_out;

    const long long n4 = (long long)out_size / 4;  // 16,777,216 float4s

    const int block = 256;
    long long blocks_needed = (n4 + block - 1) / block;
    int grid = (int)((blocks_needed < 2048) ? blocks_needed : 2048);

    ic_adjust_kernel<<<grid, block, 0, stream>>>(x, a, out, n4);
}

// Round 4
// 130.388 us; speedup vs baseline: 1.0547x; 1.0547x over previous
//
#include <hip/hip_runtime.h>

// out[i, j] = x[i, j] * a[j];  x: [65536, 1024] f32, a: [1024] f32.
// Memory-bound streaming multiply:
//  - 16B/lane fully-coalesced loads/stores (ext_vector float4)
//  - grid stride (2048*256) is a multiple of 256 column-quads -> per-thread
//    scale is loop-invariant, hoisted to a register (no LDS in hot loop)
//  - 4x unroll over stride-separated indices -> 4 independent loads in flight
//  - plain loads/stores: nt cache-bypass REGRESSED (R3: 137us vs 112us) --
//    streaming writes want L2 aggregation
//  - 32-bit index math: total buffer is 256 MiB, byte offsets fit uint32

#define XSIZE 1024
#define XSIZE4 (XSIZE / 4)   // 256 float4 column-quads

typedef float f4 __attribute__((ext_vector_type(4)));

__global__ __launch_bounds__(256) void ic_adjust_kernel(
    const float* __restrict__ x,
    const float* __restrict__ a,
    float* __restrict__ out,
    int n4) {
    const f4* __restrict__ x4 = reinterpret_cast<const f4*>(x);
    const f4* __restrict__ a4 = reinterpret_cast<const f4*>(a);
    f4* __restrict__ o4 = reinterpret_cast<f4*>(out);

    const int tid = blockIdx.x * blockDim.x + threadIdx.x;
    const int stride = gridDim.x * blockDim.x;

    // stride % XSIZE4 == 0, so (i & 255) is invariant across the grid-stride
    // loop: load this thread's column-quad scale once.
    const f4 s = a4[tid & (XSIZE4 - 1)];

    constexpr int U = 4;
    int i = tid;
    for (; i + (U - 1) * stride < n4; i += U * stride) {
        f4 v0 = x4[i];
        f4 v1 = x4[i + stride];
        f4 v2 = x4[i + 2 * stride];
        f4 v3 = x4[i + 3 * stride];
        o4[i] = v0 * s;
        o4[i + stride] = v1 * s;
        o4[i + 2 * stride] = v2 * s;
        o4[i + 3 * stride] = v3 * s;
    }
    // tail (not taken for the benchmark shape: 32 iters % 4 == 0)
    for (; i < n4; i += stride) {
        o4[i] = x4[i] * s;
    }
}

extern "C" void kernel_launch(void* const* d_in, const int* in_sizes, int n_in,
                              void* d_out, int out_size, void* d_ws, size_t ws_size,
                              hipStream_t stream) {
    const float* x = (const float*)d_in[0];
    const float* a = (const float*)d_in[1];
    float* out = (float*)d_out;

    const int n4 = out_size / 4;  // 16,777,216 float4s

    const int block = 256;
    int blocks_needed = (n4 + block - 1) / block;
    int grid = (blocks_needed < 2048) ? blocks_needed : 2048;

    ic_adjust_kernel<<<grid, block, 0, stream>>>(x, a, out, n4);
}

// Round 5
// 85.817 us; speedup vs baseline: 1.6025x; 1.5194x over previous
//
#include <hip/hip_runtime.h>

// out[i, j] = x[i, j] * a[j];  x: [65536, 1024] f32, a: [1024] f32.
//
// Counter-driven design (R4 profile):
//  - x (256 MiB) half-hits the 256 MiB Infinity Cache (FETCH was 128 MiB,
//    not 256): out's write-allocations evict half of x each pass.
//  - Fix: NONTEMPORAL STORES ONLY -> out doesn't displace x from L3;
//    x becomes (mostly) L3-resident across replays, FETCH -> ~0.
//  - Loads stay cached (R3 showed nt loads force all of x to HBM: -22%).
//  - Simple grid-stride loop (R4 showed 4x stride-separated unroll hurt).
//  - Scale hoisted to a register: grid stride (2048*256) is a multiple of
//    256 column-quads so (i & 255) is loop-invariant.
//  - 32-bit index math (byte offsets fit uint32 at 256 MiB).

#define XSIZE 1024
#define XSIZE4 (XSIZE / 4)   // 256 float4 column-quads

typedef float f4 __attribute__((ext_vector_type(4)));

__global__ __launch_bounds__(256) void ic_adjust_kernel(
    const float* __restrict__ x,
    const float* __restrict__ a,
    float* __restrict__ out,
    int n4) {
    const f4* __restrict__ x4 = reinterpret_cast<const f4*>(x);
    const f4* __restrict__ a4 = reinterpret_cast<const f4*>(a);
    f4* __restrict__ o4 = reinterpret_cast<f4*>(out);

    const int tid = blockIdx.x * blockDim.x + threadIdx.x;
    const int stride = gridDim.x * blockDim.x;

    // stride % XSIZE4 == 0, so (i & 255) is invariant across the grid-stride
    // loop: load this thread's column-quad scale once.
    const f4 s = a4[tid & (XSIZE4 - 1)];

    for (int i = tid; i < n4; i += stride) {
        f4 v = x4[i];          // cached load: let L3 keep x resident
        v *= s;
        __builtin_nontemporal_store(v, &o4[i]);  // don't evict x with out
    }
}

extern "C" void kernel_launch(void* const* d_in, const int* in_sizes, int n_in,
                              void* d_out, int out_size, void* d_ws, size_t ws_size,
                              hipStream_t stream) {
    const float* x = (const float*)d_in[0];
    const float* a = (const float*)d_in[1];
    float* out = (float*)d_out;

    const int n4 = out_size / 4;  // 16,777,216 float4s

    const int block = 256;
    int blocks_needed = (n4 + block - 1) / block;
    int grid = (blocks_needed < 2048) ? blocks_needed : 2048;

    ic_adjust_kernel<<<grid, block, 0, stream>>>(x, a, out, n4);
}